// Round 16
// baseline (48.968 us; speedup 1.0000x reference)
//
#include <hip/hip_runtime.h>

#define CIN   64
#define HW    128
#define COUT  128
#define TH    8
#define TW    32
#define NITER 12
#define NTHR  512
#define HSTR  144            // bytes per histogram row (16B aligned)
#define SLOT  (34 * HSTR)    // 4896 B per H ring slot (34 padded px)
#define H3SL  (32 * HSTR)    // 4608 B per H3 ring slot (32 out px)

// LDS layout (bytes):
//   [0, 19584)        Hm[4] ring slots, 34 rows x 144 B
//   [19584, 38016)    H3[4] ring slots, 32 rows x 144 B (Kt i8[16384]
//                     overlays this region during the prologue only)
//   [38016, 39616)    SxRaw int[10][40]: per-row per-pixel (pc<<20)|ps
//   [39616, 40896)    Sx9 int[8][40]: final 9-window sums per out-row
#define HM_OFF    0
#define H3_OFF    19584
#define SXR_OFF   38016
#define SX9_OFF   39616
#define LDS_BYTES 40896

typedef int v4i __attribute__((ext_vector_type(4)));

// lgkm-only barrier: drains LDS ops, leaves global loads/stores in flight.
__device__ __forceinline__ void wg_barrier() {
  asm volatile("s_waitcnt lgkmcnt(0)\n\ts_barrier" ::: "memory");
}

// VALU-only reductions (DPP): quad sums, then 16-lane total in lanes 12-15.
__device__ __forceinline__ int quad_sum(int v) {
  v += __builtin_amdgcn_mov_dpp(v, 0xB1, 0xF, 0xF, true);   // quad_perm xor1
  v += __builtin_amdgcn_mov_dpp(v, 0x4E, 0xF, 0xF, true);   // quad_perm xor2
  return v;
}
__device__ __forceinline__ int row16_sum(int v) {
  v = quad_sum(v);
  v += __builtin_amdgcn_mov_dpp(v, 0x114, 0xF, 0xF, true);  // row_shr:4
  v += __builtin_amdgcn_mov_dpp(v, 0x118, 0xF, 0xF, true);  // row_shr:8
  return v;                                                 // lanes 12-15: total
}

// ---------------------------------------------------------------------------
// Kernel 1: W_tab[o] = sum of quantized weights; Kt_g[o][v] i8 = K[v][o]-128
// where K[v][o] = #{w in o : qw*(128+v) > 32767}, v=0..127 (K<=255, ~7 sigma).
// ---------------------------------------------------------------------------
__global__ __launch_bounds__(512)
void build_tables(const float* __restrict__ weight, int* __restrict__ W_tab,
                  char* __restrict__ Kt_g) {
  __shared__ int qw_s[576];
  __shared__ int red_s[144];
  const int o = blockIdx.x;
  const int t = threadIdx.x;
  for (int j = t; j < 576; j += 512) {
    float w = weight[o * 576 + j];
    int q = (int)rintf(w * 255.f);
    qw_s[j] = q < 0 ? 0 : (q > 255 ? 255 : q);
  }
  __syncthreads();
  const int v = t >> 2, part = t & 3;
  const int i = 128 + v;                     // v==0 -> cnt=0 (qw*128<=32640)
  int cnt = 0;
  const int j0 = part * 144;
  for (int j = j0; j < j0 + 144; ++j) cnt += (qw_s[j] * i) > 32767 ? 1 : 0;
  cnt = quad_sum(cnt);
  if (part == 0) Kt_g[o * 128 + v] = (char)(cnt - 128);
  if (t < 144)
    red_s[t] = qw_s[t * 4] + qw_s[t * 4 + 1] + qw_s[t * 4 + 2] + qw_s[t * 4 + 3];
  __syncthreads();
  if (t == 0) {
    int s = 0;
    for (int kk = 0; kk < 144; ++kk) s += red_s[kk];
    W_tab[o] = s;
  }
}

// ---------------------------------------------------------------------------
// Kernel 2: register-resident quantized rows. Pre-pass: load + quantize ALL
// 10 input rows into qd[10] (packed 4 idx/dword, static-indexed via full
// unroll), per-pixel sums via DPP row-sum (no LDS tree), full Sx9 window
// table built once. Loop (12 iters, 1 barrier each) is only: HIST atomics
// from registers | H3 horizontal-3-sum | MFMA (K=384 vertical) + in-register
// emit | zero next H slot. No global loads, no quantize, no Sx in-loop.
// grid = 512 blocks 1D, XCD-remapped (b=bid&7). ~41 KB LDS, 2 blocks/CU.
// ---------------------------------------------------------------------------
__global__ __launch_bounds__(NTHR, 4)
void pcilt_main(const float* __restrict__ x, const float* __restrict__ bias,
                const int* __restrict__ W_tab, const char* __restrict__ Kt_g,
                float* __restrict__ out) {
  __shared__ uint4 ldsv[LDS_BYTES / 16];
  char* ldsb = (char*)ldsv;
  unsigned char* HmB = (unsigned char*)(ldsb + HM_OFF);
  unsigned char* H3B = (unsigned char*)(ldsb + H3_OFF);
  unsigned char* KtB = (unsigned char*)(ldsb + H3_OFF);   // prologue overlay
  int* SxR = (int*)(ldsb + SXR_OFF);                      // [10][40]
  int* Sx9 = (int*)(ldsb + SX9_OFF);                      // [8][40]

  const int t   = (int)threadIdx.x;
  const int bid = (int)blockIdx.x;
  const int b  = bid & 7;                                 // XCD owns one batch
  const int k  = bid >> 3;
  const int h0 = (k >> 2) * TH;
  const int w0 = (k & 3) * TW;

  for (int i = t; i < 4096; i += NTHR)
    ((unsigned int*)KtB)[i] = ((const unsigned int*)Kt_g)[i];
  {
    const uint4 z4 = make_uint4(0, 0, 0, 0);
    for (int i = t; i < SLOT / 16; i += NTHR) ((uint4*)HmB)[i] = z4;  // H[0]
  }

  const int l    = t & 15;
  const int slot = t >> 4;
  const int wv   = t >> 6;
  const int kq   = (t >> 4) & 3;
  const int Mt   = wv >> 2;                // 0..1: px tile
  const int Nh   = wv & 3;                 // 0..3: o quarter
  const int o0   = Nh * 32 + l;            // thread's o (second frag +16)

  const float wfo0 = (float)W_tab[o0],      bio0 = bias[o0];
  const float wfo1 = (float)W_tab[o0 + 16], bio1 = bias[o0 + 16];

  wg_barrier();                                  // Kt + H[0] zero visible

  // hoist B-fragments from Kt (H3 region unread until first write at r=1)
  v4i bfr[2][2];
#pragma unroll
  for (int nt = 0; nt < 2; ++nt)
#pragma unroll
    for (int k64 = 0; k64 < 2; ++k64)
      bfr[nt][k64] = *(const v4i*)(KtB + (o0 + nt * 16) * 128 + k64 * 64 + kq * 16);

  // -------- pre-pass: quantize all 10 rows into registers ------------------
  unsigned int qd[10], qd2[10];
  {
    const float* xb = x + ((size_t)b * CIN + l * 4) * (HW * HW);
    const size_t cs = (size_t)HW * HW;
    const int ix0 = w0 + slot - 1;
    const int ix0c = ix0 < 0 ? 0 : (ix0 > 127 ? 127 : ix0);
    const bool wok0 = (ix0 >= 0) && (ix0 < HW);
    const int ix1 = w0 + slot + 1;                // px slot+2 (slots 30,31)
    const int ix1c = ix1 > 127 ? 127 : ix1;
    const bool wok1 = ix1 < HW;
    const bool dual = slot >= 30;
#pragma unroll
    for (int row = 0; row < 10; ++row) {
      const int iy = h0 + row - 1;
      const int iyc = iy < 0 ? 0 : (iy > 127 ? 127 : iy);
      const bool rok = (iy >= 0) && (iy < HW);
      {
        const float* xp = xb + (size_t)iyc * HW + ix0c;
        const bool ok = rok && wok0;
        float f0 = xp[0], f1 = xp[cs], f2 = xp[2 * cs], f3 = xp[3 * cs];
        f0 = ok ? f0 : 0.f; f1 = ok ? f1 : 0.f; f2 = ok ? f2 : 0.f; f3 = ok ? f3 : 0.f;
        int q0 = (int)rintf(f0 * 255.f); q0 = q0 < 0 ? 0 : (q0 > 255 ? 255 : q0);
        int q1 = (int)rintf(f1 * 255.f); q1 = q1 < 0 ? 0 : (q1 > 255 ? 255 : q1);
        int q2 = (int)rintf(f2 * 255.f); q2 = q2 < 0 ? 0 : (q2 > 255 ? 255 : q2);
        int q3 = (int)rintf(f3 * 255.f); q3 = q3 < 0 ? 0 : (q3 > 255 ? 255 : q3);
        qd[row] = (unsigned)q0 | ((unsigned)q1 << 8) | ((unsigned)q2 << 16) | ((unsigned)q3 << 24);
        int pk = (((q0 > 128) + (q1 > 128) + (q2 > 128) + (q3 > 128)) << 20) +
                 (q0 + q1 + q2 + q3);
        pk = row16_sum(pk);
        if (l == 15) SxR[row * 40 + slot] = pk;
      }
      {
        const float* xp = xb + (size_t)iyc * HW + ix1c;
        const bool ok = dual && rok && wok1;
        float f0 = ok ? xp[0] : 0.f, f1 = ok ? xp[cs] : 0.f;
        float f2 = ok ? xp[2 * cs] : 0.f, f3 = ok ? xp[3 * cs] : 0.f;
        int q0 = (int)rintf(f0 * 255.f); q0 = q0 < 0 ? 0 : (q0 > 255 ? 255 : q0);
        int q1 = (int)rintf(f1 * 255.f); q1 = q1 < 0 ? 0 : (q1 > 255 ? 255 : q1);
        int q2 = (int)rintf(f2 * 255.f); q2 = q2 < 0 ? 0 : (q2 > 255 ? 255 : q2);
        int q3 = (int)rintf(f3 * 255.f); q3 = q3 < 0 ? 0 : (q3 > 255 ? 255 : q3);
        qd2[row] = (unsigned)q0 | ((unsigned)q1 << 8) | ((unsigned)q2 << 16) | ((unsigned)q3 << 24);
        int pk = (((q0 > 128) + (q1 > 128) + (q2 > 128) + (q3 > 128)) << 20) +
                 (q0 + q1 + q2 + q3);
        pk = row16_sum(pk);
        if (dual && l == 15) SxR[row * 40 + slot + 2] = pk;
      }
    }
  }
  wg_barrier();                                  // SxR + bfr complete

#define HISTD(dw, px, Hc)                                                      \
  {                                                                            \
    unsigned char* hp = (Hc) + (px)*HSTR;                                      \
    const unsigned b0 = (dw) & 255u, b1 = ((dw) >> 8) & 255u;                  \
    const unsigned b2 = ((dw) >> 16) & 255u, b3 = (dw) >> 24;                  \
    if (b0 > 128u) { unsigned v = b0 - 128u; atomicAdd((unsigned*)(hp + ((v >> 2) << 2)), 1u << ((v & 3) * 8)); } \
    if (b1 > 128u) { unsigned v = b1 - 128u; atomicAdd((unsigned*)(hp + ((v >> 2) << 2)), 1u << ((v & 3) * 8)); } \
    if (b2 > 128u) { unsigned v = b2 - 128u; atomicAdd((unsigned*)(hp + ((v >> 2) << 2)), 1u << ((v & 3) * 8)); } \
    if (b3 > 128u) { unsigned v = b3 - 128u; atomicAdd((unsigned*)(hp + ((v >> 2) << 2)), 1u << ((v & 3) * 8)); } \
  }

#pragma unroll
  for (int r = 0; r < NITER; ++r) {
    // ---- (a) histogram atomics for row r, straight from registers ---------
    if (r <= 9) {
      unsigned char* Hc = HmB + (r & 3) * SLOT;
      HISTD(qd[r], slot, Hc);
      if (slot >= 30) HISTD(qd2[r], slot + 2, Hc);
    }
    // ---- (b) Sx9 table, once (waves 0-3 are otherwise idle at r=0) --------
    if (r == 0 && t < 256) {
      const int j = t >> 5, L = t & 31;
      int v9 = 0;
#pragma unroll
      for (int q = 0; q < 3; ++q) {
        const int* sr = &SxR[(j + q) * 40 + L];
        v9 += sr[0] + sr[1] + sr[2];
      }
      Sx9[j * 40 + L] = v9;
    }
    // ---- (c) H3[r-1]: horizontal 3-sum, u8-exact dword adds ---------------
    if (r >= 1 && r <= 10 && t < 256) {
      const int px = t & 31, ch = (t >> 5) * 16;
      const unsigned char* hs = HmB + ((r - 1) & 3) * SLOT + px * HSTR + ch;
      const uint4 a0 = *(const uint4*)hs;
      const uint4 a1 = *(const uint4*)(hs + HSTR);
      const uint4 a2 = *(const uint4*)(hs + 2 * HSTR);
      uint4 s;
      s.x = a0.x + a1.x + a2.x; s.y = a0.y + a1.y + a2.y;
      s.z = a0.z + a1.z + a2.z; s.w = a0.w + a1.w + a2.w;
      *(uint4*)(H3B + ((r - 1) & 3) * H3SL + px * HSTR + ch) = s;
    }
    // ---- (d) MFMA out-row j=r-4 + in-register emit ------------------------
    if (r >= 4) {
      v4i acc0 = (v4i){0, 0, 0, 0}, acc1 = (v4i){0, 0, 0, 0};
#pragma unroll
      for (int st = 0; st < 3; ++st) {
        const unsigned char* Hs = H3B + ((r - 4 + st) & 3) * H3SL +
                                  (Mt * 16 + l) * HSTR + kq * 16;
#pragma unroll
        for (int k64 = 0; k64 < 2; ++k64) {
          const v4i a = *(const v4i*)(Hs + k64 * 64);
          acc0 = __builtin_amdgcn_mfma_i32_16x16x64_i8(a, bfr[0][k64], acc0, 0, 0, 0);
          acc1 = __builtin_amdgcn_mfma_i32_16x16x64_i8(a, bfr[1][k64], acc1, 0, 0, 0);
        }
      }
      const int j = r - 4, h = h0 + j, px0 = Mt * 16 + kq * 4;
      const v4i s9 = *(const v4i*)&Sx9[j * 40 + px0];
      float4 u0, u1;
#pragma unroll
      for (int rg = 0; rg < 4; ++rg) {
        const int sx = s9[rg] & 0xFFFFF;
        const int sh = s9[rg] >> 20;
        ((float*)&u0)[rg] = (float)sx * wfo0 - 65536.f * (float)(acc0[rg] + (sh << 7)) + bio0;
        ((float*)&u1)[rg] = (float)sx * wfo1 - 65536.f * (float)(acc1[rg] + (sh << 7)) + bio1;
      }
      float* op = out + (((size_t)b * COUT + o0) * HW + h) * HW + w0 + px0;
      *(float4*)op = u0;
      *(float4*)(op + 16 * (size_t)(HW * HW)) = u1;
    }
    // ---- (e) waves 4-5: zero H slot r+1 -----------------------------------
    if (r <= 8 && wv >= 4 && wv < 6) {
      uint4* Hn = (uint4*)(HmB + ((r + 1) & 3) * SLOT);
      const uint4 z4 = make_uint4(0, 0, 0, 0);
      for (int i2 = t - 256; i2 < SLOT / 16; i2 += 128) Hn[i2] = z4;
    }
    wg_barrier();
  }
}

// ---------------------------------------------------------------------------
extern "C" void kernel_launch(void* const* d_in, const int* in_sizes, int n_in,
                              void* d_out, int out_size, void* d_ws, size_t ws_size,
                              hipStream_t stream) {
  const float* x      = (const float*)d_in[0];
  const float* weight = (const float*)d_in[1];
  const float* bias   = (const float*)d_in[2];
  float* out = (float*)d_out;

  int*  W_tab = (int*)d_ws;
  char* Kt_g  = (char*)d_ws + 512;

  build_tables<<<128, 512, 0, stream>>>(weight, W_tab, Kt_g);

  pcilt_main<<<512, NTHR, 0, stream>>>(x, bias, W_tab, Kt_g, out);
}